// Round 1
// baseline (267.443 us; speedup 1.0000x reference)
//
#include <hip/hip_runtime.h>

#define ROI_OUT_H 7
#define ROI_OUT_W 7
#define ROI_SPATIAL_SCALE 0.125f

// features: (B=8, C=256, H=100, W=100) fp32, NCHW
// rois:     (N, 5) fp32  [batch_idx, x1, y1, x2, y2]
// out:      (N, C, 7, 7) fp32

__global__ __launch_bounds__(256) void roi_align_kernel(
    const float* __restrict__ features,
    const float* __restrict__ rois,
    float* __restrict__ out,
    int n_total, int C, int H, int W)
{
    const int HW = H * W;
    int idx = blockIdx.x * 256 + threadIdx.x;
    if (idx >= n_total) return;

    int pw  = idx % ROI_OUT_W;
    int ph  = (idx / ROI_OUT_W) % ROI_OUT_H;
    int c   = (idx / (ROI_OUT_H * ROI_OUT_W)) % 256;
    int n   = idx / (ROI_OUT_H * ROI_OUT_W * 256);

    const float* roi = rois + (size_t)n * 5;
    int   b  = (int)roi[0];
    float x1 = roi[1] * ROI_SPATIAL_SCALE;
    float y1 = roi[2] * ROI_SPATIAL_SCALE;
    float x2 = roi[3] * ROI_SPATIAL_SCALE;
    float y2 = roi[4] * ROI_SPATIAL_SCALE;

    float roi_w = fmaxf(x2 - x1, 1.0f);
    float roi_h = fmaxf(y2 - y1, 1.0f);
    float bin_w = roi_w * (1.0f / ROI_OUT_W);
    float bin_h = roi_h * (1.0f / ROI_OUT_H);

    const float* img = features + ((size_t)b * C + c) * HW;

    float acc = 0.0f;

    #pragma unroll
    for (int sy = 0; sy < 2; ++sy) {
        float y = y1 + (float)ph * bin_h + ((float)sy + 0.5f) * bin_h * 0.5f;
        bool  vy = (y > -1.0f) && (y < (float)H);
        float yc = fmaxf(y, 0.0f);
        int   y_low = (int)floorf(yc);
        int   y_high;
        if (y_low >= H - 1) { y_low = H - 1; y_high = H - 1; yc = (float)y_low; }
        else                { y_high = y_low + 1; }
        float ly = yc - (float)y_low;
        float hy = 1.0f - ly;

        #pragma unroll
        for (int sx = 0; sx < 2; ++sx) {
            float x = x1 + (float)pw * bin_w + ((float)sx + 0.5f) * bin_w * 0.5f;
            bool  vx = (x > -1.0f) && (x < (float)W);
            float xc = fmaxf(x, 0.0f);
            int   x_low = (int)floorf(xc);
            int   x_high;
            if (x_low >= W - 1) { x_low = W - 1; x_high = W - 1; xc = (float)x_low; }
            else                { x_high = x_low + 1; }
            float lx = xc - (float)x_low;
            float hx = 1.0f - lx;

            int base_lo = y_low  * W;
            int base_hi = y_high * W;
            float v1 = img[base_lo + x_low];
            float v2 = img[base_lo + x_high];
            float v3 = img[base_hi + x_low];
            float v4 = img[base_hi + x_high];

            float val = hy * hx * v1 + hy * lx * v2 + ly * hx * v3 + ly * lx * v4;
            acc += (vy && vx) ? val : 0.0f;
        }
    }

    out[idx] = acc * 0.25f;
}

extern "C" void kernel_launch(void* const* d_in, const int* in_sizes, int n_in,
                              void* d_out, int out_size, void* d_ws, size_t ws_size,
                              hipStream_t stream)
{
    const float* features = (const float*)d_in[0];
    const float* rois     = (const float*)d_in[1];
    float*       out      = (float*)d_out;

    const int C = 256, H = 100, W = 100;
    int n_rois  = in_sizes[1] / 5;           // 1000
    int n_total = n_rois * C * ROI_OUT_H * ROI_OUT_W;  // == out_size

    int grid = (n_total + 255) / 256;
    roi_align_kernel<<<grid, 256, 0, stream>>>(features, rois, out, n_total, C, H, W);
}

// Round 2
// 222.371 us; speedup vs baseline: 1.2027x; 1.2027x over previous
//
#include <hip/hip_runtime.h>

#define ROI_OUT_H 7
#define ROI_OUT_W 7
#define ROI_SPATIAL_SCALE 0.125f

// features: (B=8, C=256, H=100, W=100) fp32 NCHW
// rois:     (N, 5) fp32  [batch_idx, x1, y1, x2, y2]
// out:      (N, C, 7, 7) fp32

// ---------------------------------------------------------------------------
// Kernel 1: NCHW -> NHWC transpose (64c x 64x LDS tile per (b,y))
// ---------------------------------------------------------------------------
__global__ __launch_bounds__(256) void nchw_to_nhwc(
    const float* __restrict__ src, float* __restrict__ dst)
{
    constexpr int C = 256, H = 100, W = 100;
    __shared__ float tile[64][65];

    int bid = blockIdx.x;
    int ct = bid & 3;           // 4 c-tiles of 64
    int xt = (bid >> 2) & 1;    // 2 x-tiles of 64
    int y  = (bid >> 3) % 100;
    int b  = bid / 800;

    int tx = threadIdx.x & 63;
    int ty = threadIdx.x >> 6;  // 0..3
    int c0 = ct * 64, x0 = xt * 64;

    int x = x0 + tx;
    if (x < W) {
        #pragma unroll
        for (int i = 0; i < 16; ++i) {
            int cl = i * 4 + ty;
            tile[cl][tx] = src[(((size_t)b * C + (c0 + cl)) * H + y) * W + x];
        }
    }
    __syncthreads();

    int c = c0 + tx;
    #pragma unroll
    for (int i = 0; i < 16; ++i) {
        int xl = i * 4 + ty;
        int xx = x0 + xl;
        if (xx < W)
            dst[(((size_t)b * H + y) * W + xx) * C + c] = tile[tx][xl];
    }
}

// ---------------------------------------------------------------------------
// Kernel 2: RoIAlign on NHWC. One block per roi; lane = channel.
// All corner loads are base_uniform + tid -> perfectly coalesced.
// ---------------------------------------------------------------------------
__global__ __launch_bounds__(256) void roi_align_nhwc(
    const float* __restrict__ nhwc,
    const float* __restrict__ rois,
    float* __restrict__ out)
{
    constexpr int C = 256, H = 100, W = 100;
    __shared__ float sbuf[256 * 50];   // [c][49 + 1 pad]

    int n   = blockIdx.x;
    int tid = threadIdx.x;             // channel

    const float* roi = rois + (size_t)n * 5;
    int   b  = (int)roi[0];
    float x1 = roi[1] * ROI_SPATIAL_SCALE;
    float y1 = roi[2] * ROI_SPATIAL_SCALE;
    float x2 = roi[3] * ROI_SPATIAL_SCALE;
    float y2 = roi[4] * ROI_SPATIAL_SCALE;

    float roi_w = fmaxf(x2 - x1, 1.0f);
    float roi_h = fmaxf(y2 - y1, 1.0f);
    float bin_w = roi_w * (1.0f / ROI_OUT_W);
    float bin_h = roi_h * (1.0f / ROI_OUT_H);

    const float* img = nhwc + (size_t)b * (H * W * C);

    // x-side precompute (pw, sx): offsets + validity-folded weights
    int   xoffl[7][2], xoffh[7][2];
    float xwh[7][2], xwl[7][2];        // weight for x_low / x_high
    #pragma unroll
    for (int pw = 0; pw < 7; ++pw) {
        #pragma unroll
        for (int sx = 0; sx < 2; ++sx) {
            float xx = x1 + (float)pw * bin_w + ((float)sx + 0.5f) * bin_w * 0.5f;
            float vx = (xx > -1.0f && xx < (float)W) ? 1.0f : 0.0f;
            float xc = fmaxf(xx, 0.0f);
            int x_low = (int)floorf(xc);
            int x_high;
            if (x_low >= W - 1) { x_low = W - 1; x_high = W - 1; xc = (float)x_low; }
            else                { x_high = x_low + 1; }
            float lx = xc - (float)x_low;
            xoffl[pw][sx] = x_low  * C;
            xoffh[pw][sx] = x_high * C;
            xwh[pw][sx] = (1.0f - lx) * vx;
            xwl[pw][sx] = lx * vx;
        }
    }

    for (int ph = 0; ph < 7; ++ph) {
        // y-side for this ph (validity folded into weights)
        int   yoffl[2], yoffh[2];
        float ywh[2], ywl[2];
        #pragma unroll
        for (int sy = 0; sy < 2; ++sy) {
            float yy = y1 + (float)ph * bin_h + ((float)sy + 0.5f) * bin_h * 0.5f;
            float vy = (yy > -1.0f && yy < (float)H) ? 1.0f : 0.0f;
            float yc = fmaxf(yy, 0.0f);
            int y_low = (int)floorf(yc);
            int y_high;
            if (y_low >= H - 1) { y_low = H - 1; y_high = H - 1; yc = (float)y_low; }
            else                { y_high = y_low + 1; }
            float ly = yc - (float)y_low;
            yoffl[sy] = y_low  * (W * C);
            yoffh[sy] = y_high * (W * C);
            ywh[sy] = (1.0f - ly) * vy;
            ywl[sy] = ly * vy;
        }

        #pragma unroll
        for (int pw = 0; pw < 7; ++pw) {
            float acc = 0.0f;
            #pragma unroll
            for (int sy = 0; sy < 2; ++sy) {
                #pragma unroll
                for (int sx = 0; sx < 2; ++sx) {
                    float v1 = img[yoffl[sy] + xoffl[pw][sx] + tid];
                    float v2 = img[yoffl[sy] + xoffh[pw][sx] + tid];
                    float v3 = img[yoffh[sy] + xoffl[pw][sx] + tid];
                    float v4 = img[yoffh[sy] + xoffh[pw][sx] + tid];
                    acc += ywh[sy] * (xwh[pw][sx] * v1 + xwl[pw][sx] * v2)
                         + ywl[sy] * (xwh[pw][sx] * v3 + xwl[pw][sx] * v4);
                }
            }
            sbuf[tid * 50 + ph * 7 + pw] = acc * 0.25f;
        }
    }
    __syncthreads();

    // coalesced output write: out flat order within roi is (c, ph, pw)
    size_t obase = (size_t)n * (C * 49);
    #pragma unroll
    for (int k = 0; k < 49; ++k) {
        int flat = k * 256 + tid;
        int c    = flat / 49;
        int bin  = flat - c * 49;
        out[obase + flat] = sbuf[c * 50 + bin];
    }
}

// ---------------------------------------------------------------------------
// Fallback (round-0 kernel) if workspace is too small for NHWC copy
// ---------------------------------------------------------------------------
__global__ __launch_bounds__(256) void roi_align_kernel(
    const float* __restrict__ features,
    const float* __restrict__ rois,
    float* __restrict__ out,
    int n_total, int C, int H, int W)
{
    const int HW = H * W;
    int idx = blockIdx.x * 256 + threadIdx.x;
    if (idx >= n_total) return;

    int pw  = idx % ROI_OUT_W;
    int ph  = (idx / ROI_OUT_W) % ROI_OUT_H;
    int c   = (idx / (ROI_OUT_H * ROI_OUT_W)) % 256;
    int n   = idx / (ROI_OUT_H * ROI_OUT_W * 256);

    const float* roi = rois + (size_t)n * 5;
    int   b  = (int)roi[0];
    float x1 = roi[1] * ROI_SPATIAL_SCALE;
    float y1 = roi[2] * ROI_SPATIAL_SCALE;
    float x2 = roi[3] * ROI_SPATIAL_SCALE;
    float y2 = roi[4] * ROI_SPATIAL_SCALE;

    float roi_w = fmaxf(x2 - x1, 1.0f);
    float roi_h = fmaxf(y2 - y1, 1.0f);
    float bin_w = roi_w * (1.0f / ROI_OUT_W);
    float bin_h = roi_h * (1.0f / ROI_OUT_H);

    const float* img = features + ((size_t)b * C + c) * HW;
    float acc = 0.0f;

    #pragma unroll
    for (int sy = 0; sy < 2; ++sy) {
        float y = y1 + (float)ph * bin_h + ((float)sy + 0.5f) * bin_h * 0.5f;
        bool  vy = (y > -1.0f) && (y < (float)H);
        float yc = fmaxf(y, 0.0f);
        int   y_low = (int)floorf(yc);
        int   y_high;
        if (y_low >= H - 1) { y_low = H - 1; y_high = H - 1; yc = (float)y_low; }
        else                { y_high = y_low + 1; }
        float ly = yc - (float)y_low;
        float hy = 1.0f - ly;

        #pragma unroll
        for (int sx = 0; sx < 2; ++sx) {
            float x = x1 + (float)pw * bin_w + ((float)sx + 0.5f) * bin_w * 0.5f;
            bool  vx = (x > -1.0f) && (x < (float)W);
            float xc = fmaxf(x, 0.0f);
            int   x_low = (int)floorf(xc);
            int   x_high;
            if (x_low >= W - 1) { x_low = W - 1; x_high = W - 1; xc = (float)x_low; }
            else                { x_high = x_low + 1; }
            float lx = xc - (float)x_low;
            float hx = 1.0f - lx;

            int base_lo = y_low  * W;
            int base_hi = y_high * W;
            float v1 = img[base_lo + x_low];
            float v2 = img[base_lo + x_high];
            float v3 = img[base_hi + x_low];
            float v4 = img[base_hi + x_high];

            float val = hy * hx * v1 + hy * lx * v2 + ly * hx * v3 + ly * lx * v4;
            acc += (vy && vx) ? val : 0.0f;
        }
    }
    out[idx] = acc * 0.25f;
}

extern "C" void kernel_launch(void* const* d_in, const int* in_sizes, int n_in,
                              void* d_out, int out_size, void* d_ws, size_t ws_size,
                              hipStream_t stream)
{
    const float* features = (const float*)d_in[0];
    const float* rois     = (const float*)d_in[1];
    float*       out      = (float*)d_out;

    const int C = 256, H = 100, W = 100, B = 8;
    int n_rois = in_sizes[1] / 5;   // 1000

    size_t nhwc_bytes = (size_t)B * H * W * C * sizeof(float);  // 81.92 MB

    if (ws_size >= nhwc_bytes) {
        float* nhwc = (float*)d_ws;
        nchw_to_nhwc<<<B * H * 2 * 4, 256, 0, stream>>>(features, nhwc);
        roi_align_nhwc<<<n_rois, 256, 0, stream>>>(nhwc, rois, out);
    } else {
        int n_total = n_rois * C * ROI_OUT_H * ROI_OUT_W;
        int grid = (n_total + 255) / 256;
        roi_align_kernel<<<grid, 256, 0, stream>>>(features, rois, out, n_total, C, H, W);
    }
}

// Round 3
// 217.595 us; speedup vs baseline: 1.2291x; 1.0219x over previous
//
#include <hip/hip_runtime.h>

#define ROI_OUT_H 7
#define ROI_OUT_W 7
#define ROI_SPATIAL_SCALE 0.125f

// features: (B=8, C=256, H=100, W=100) fp32 NCHW
// rois:     (N, 5) fp32  [batch_idx, x1, y1, x2, y2]
// out:      (N, C, 7, 7) fp32

// ---------------------------------------------------------------------------
// Kernel 1: NCHW -> NHWC transpose, float4 on both sides (1 KB/wave-instr)
// 64c x 64x tile per (b, y, ct, xt)
// ---------------------------------------------------------------------------
__global__ __launch_bounds__(256) void nchw_to_nhwc(
    const float* __restrict__ src, float* __restrict__ dst)
{
    constexpr int C = 256, H = 100, W = 100;
    __shared__ float tile[64][65];

    int bid = blockIdx.x;
    int ct = bid & 3;           // 4 c-tiles of 64
    int xt = (bid >> 2) & 1;    // 2 x-tiles of 64
    int y  = (bid >> 3) % H;
    int b  = bid / (H * 8);

    int t  = threadIdx.x;
    int c0 = ct * 64, x0 = xt * 64;

    // load: float4 along x. 16 lanes span 64 x; 16 c-rows per iter.
    int xq = t & 15;
    int cr = t >> 4;            // 0..15
    #pragma unroll
    for (int i = 0; i < 4; ++i) {
        int c = i * 16 + cr;
        int x = x0 + 4 * xq;
        if (x < W) {            // W%4==0 so x<W => x+3<W
            const float4 v = *reinterpret_cast<const float4*>(
                &src[(((size_t)b * C + (c0 + c)) * H + y) * W + x]);
            tile[c][4 * xq + 0] = v.x;
            tile[c][4 * xq + 1] = v.y;
            tile[c][4 * xq + 2] = v.z;
            tile[c][4 * xq + 3] = v.w;
        }
    }
    __syncthreads();

    // store: float4 along c. 16 lanes (cq) span 64 c; 16 x-rows per iter.
    int cq = t & 15;
    int xr = t >> 4;
    #pragma unroll
    for (int i = 0; i < 4; ++i) {
        int xl = i * 16 + xr;
        int x  = x0 + xl;
        if (x < W) {
            float4 v;
            v.x = tile[4 * cq + 0][xl];
            v.y = tile[4 * cq + 1][xl];
            v.z = tile[4 * cq + 2][xl];
            v.w = tile[4 * cq + 3][xl];
            *reinterpret_cast<float4*>(
                &dst[(((size_t)b * H + y) * W + x) * C + c0 + 4 * cq]) = v;
        }
    }
}

// ---------------------------------------------------------------------------
// Kernel 2: RoIAlign on NHWC. One WAVE per (roi, c-quarter); lane = channel.
// 12.5 KB LDS -> 12 blocks/CU; XCD-bijective grouping keeps a roi's quarters
// and neighboring rois on one XCD's L2.
// ---------------------------------------------------------------------------
__global__ __launch_bounds__(64, 4) void roi_align_nhwc_q(
    const float* __restrict__ nhwc,
    const float* __restrict__ rois,
    float* __restrict__ out,
    int nwg)
{
    constexpr int C = 256, H = 100, W = 100;
    __shared__ float sbuf[64 * 49];   // identity layout with out sub-block

    // bijective XCD swizzle (m204): blocks with the same hardware XCD
    // (bid%8) get a contiguous logical range.
    int bid = blockIdx.x;
    int q = nwg >> 3, r = nwg & 7;
    int xcd = bid & 7, pos = bid >> 3;
    int logical = (xcd < r ? xcd * (q + 1) : r * (q + 1) + (xcd - r) * q) + pos;

    int n  = logical >> 2;
    int cq = logical & 3;
    int c0 = cq * 64;
    int lane = threadIdx.x;

    const float* roi = rois + (size_t)n * 5;
    int   b  = (int)roi[0];
    float x1 = roi[1] * ROI_SPATIAL_SCALE;
    float y1 = roi[2] * ROI_SPATIAL_SCALE;
    float x2 = roi[3] * ROI_SPATIAL_SCALE;
    float y2 = roi[4] * ROI_SPATIAL_SCALE;

    float roi_w = fmaxf(x2 - x1, 1.0f);
    float roi_h = fmaxf(y2 - y1, 1.0f);
    float bin_w = roi_w * (1.0f / ROI_OUT_W);
    float bin_h = roi_h * (1.0f / ROI_OUT_H);

    const float* img = nhwc + (size_t)b * (H * W * C) + c0 + lane;

    // x-side precompute: offsets (in floats) + validity-folded weights
    int   xoffl[7][2], xoffh[7][2];
    float xwh[7][2], xwl[7][2];
    #pragma unroll
    for (int pw = 0; pw < 7; ++pw) {
        #pragma unroll
        for (int sx = 0; sx < 2; ++sx) {
            float xx = x1 + (float)pw * bin_w + ((float)sx + 0.5f) * bin_w * 0.5f;
            float vx = (xx > -1.0f && xx < (float)W) ? 1.0f : 0.0f;
            float xc = fmaxf(xx, 0.0f);
            int x_low = (int)floorf(xc);
            int x_high;
            if (x_low >= W - 1) { x_low = W - 1; x_high = W - 1; xc = (float)x_low; }
            else                { x_high = x_low + 1; }
            float lx = xc - (float)x_low;
            xoffl[pw][sx] = x_low  * C;
            xoffh[pw][sx] = x_high * C;
            xwh[pw][sx] = (1.0f - lx) * vx;
            xwl[pw][sx] = lx * vx;
        }
    }

    for (int ph = 0; ph < 7; ++ph) {
        int   yoffl[2], yoffh[2];
        float ywh[2], ywl[2];
        #pragma unroll
        for (int sy = 0; sy < 2; ++sy) {
            float yy = y1 + (float)ph * bin_h + ((float)sy + 0.5f) * bin_h * 0.5f;
            float vy = (yy > -1.0f && yy < (float)H) ? 1.0f : 0.0f;
            float yc = fmaxf(yy, 0.0f);
            int y_low = (int)floorf(yc);
            int y_high;
            if (y_low >= H - 1) { y_low = H - 1; y_high = H - 1; yc = (float)y_low; }
            else                { y_high = y_low + 1; }
            float ly = yc - (float)y_low;
            yoffl[sy] = y_low  * (W * C);
            yoffh[sy] = y_high * (W * C);
            ywh[sy] = (1.0f - ly) * vy;
            ywl[sy] = ly * vy;
        }

        #pragma unroll
        for (int pw = 0; pw < 7; ++pw) {
            float acc = 0.0f;
            #pragma unroll
            for (int sy = 0; sy < 2; ++sy) {
                #pragma unroll
                for (int sx = 0; sx < 2; ++sx) {
                    float v1 = img[yoffl[sy] + xoffl[pw][sx]];
                    float v2 = img[yoffl[sy] + xoffh[pw][sx]];
                    float v3 = img[yoffh[sy] + xoffl[pw][sx]];
                    float v4 = img[yoffh[sy] + xoffh[pw][sx]];
                    acc += ywh[sy] * (xwh[pw][sx] * v1 + xwl[pw][sx] * v2)
                         + ywl[sy] * (xwh[pw][sx] * v3 + xwl[pw][sx] * v4);
                }
            }
            sbuf[lane * 49 + ph * 7 + pw] = acc * 0.25f;
        }
    }
    __syncthreads();

    // out sub-block for (n, c0..c0+63) is 3136 contiguous floats whose layout
    // equals sbuf's flat layout -> pure streaming copy.
    size_t obase = (size_t)n * (C * 49) + (size_t)c0 * 49;
    #pragma unroll
    for (int k = 0; k < 49; ++k) {
        out[obase + k * 64 + lane] = sbuf[k * 64 + lane];
    }
}

// ---------------------------------------------------------------------------
// Fallback (round-0 kernel) if workspace is too small for the NHWC copy
// ---------------------------------------------------------------------------
__global__ __launch_bounds__(256) void roi_align_kernel(
    const float* __restrict__ features,
    const float* __restrict__ rois,
    float* __restrict__ out,
    int n_total, int C, int H, int W)
{
    const int HW = H * W;
    int idx = blockIdx.x * 256 + threadIdx.x;
    if (idx >= n_total) return;

    int pw  = idx % ROI_OUT_W;
    int ph  = (idx / ROI_OUT_W) % ROI_OUT_H;
    int c   = (idx / (ROI_OUT_H * ROI_OUT_W)) % 256;
    int n   = idx / (ROI_OUT_H * ROI_OUT_W * 256);

    const float* roi = rois + (size_t)n * 5;
    int   b  = (int)roi[0];
    float x1 = roi[1] * ROI_SPATIAL_SCALE;
    float y1 = roi[2] * ROI_SPATIAL_SCALE;
    float x2 = roi[3] * ROI_SPATIAL_SCALE;
    float y2 = roi[4] * ROI_SPATIAL_SCALE;

    float roi_w = fmaxf(x2 - x1, 1.0f);
    float roi_h = fmaxf(y2 - y1, 1.0f);
    float bin_w = roi_w * (1.0f / ROI_OUT_W);
    float bin_h = roi_h * (1.0f / ROI_OUT_H);

    const float* img = features + ((size_t)b * C + c) * HW;
    float acc = 0.0f;

    #pragma unroll
    for (int sy = 0; sy < 2; ++sy) {
        float y = y1 + (float)ph * bin_h + ((float)sy + 0.5f) * bin_h * 0.5f;
        bool  vy = (y > -1.0f) && (y < (float)H);
        float yc = fmaxf(y, 0.0f);
        int   y_low = (int)floorf(yc);
        int   y_high;
        if (y_low >= H - 1) { y_low = H - 1; y_high = H - 1; yc = (float)y_low; }
        else                { y_high = y_low + 1; }
        float ly = yc - (float)y_low;
        float hy = 1.0f - ly;

        #pragma unroll
        for (int sx = 0; sx < 2; ++sx) {
            float x = x1 + (float)pw * bin_w + ((float)sx + 0.5f) * bin_w * 0.5f;
            bool  vx = (x > -1.0f) && (x < (float)W);
            float xc = fmaxf(x, 0.0f);
            int   x_low = (int)floorf(xc);
            int   x_high;
            if (x_low >= W - 1) { x_low = W - 1; x_high = W - 1; xc = (float)x_low; }
            else                { x_high = x_low + 1; }
            float lx = xc - (float)x_low;
            float hx = 1.0f - lx;

            int base_lo = y_low  * W;
            int base_hi = y_high * W;
            float v1 = img[base_lo + x_low];
            float v2 = img[base_lo + x_high];
            float v3 = img[base_hi + x_low];
            float v4 = img[base_hi + x_high];

            float val = hy * hx * v1 + hy * lx * v2 + ly * hx * v3 + ly * lx * v4;
            acc += (vy && vx) ? val : 0.0f;
        }
    }
    out[idx] = acc * 0.25f;
}

extern "C" void kernel_launch(void* const* d_in, const int* in_sizes, int n_in,
                              void* d_out, int out_size, void* d_ws, size_t ws_size,
                              hipStream_t stream)
{
    const float* features = (const float*)d_in[0];
    const float* rois     = (const float*)d_in[1];
    float*       out      = (float*)d_out;

    const int C = 256, H = 100, W = 100, B = 8;
    int n_rois = in_sizes[1] / 5;   // 1000

    size_t nhwc_bytes = (size_t)B * H * W * C * sizeof(float);  // 81.92 MB

    if (ws_size >= nhwc_bytes) {
        float* nhwc = (float*)d_ws;
        nchw_to_nhwc<<<B * H * 2 * 4, 256, 0, stream>>>(features, nhwc);
        int nwg = n_rois * 4;
        roi_align_nhwc_q<<<nwg, 64, 0, stream>>>(nhwc, rois, out, nwg);
    } else {
        int n_total = n_rois * C * ROI_OUT_H * ROI_OUT_W;
        int grid = (n_total + 255) / 256;
        roi_align_kernel<<<grid, 256, 0, stream>>>(features, rois, out, n_total, C, H, W);
    }
}

// Round 4
// 204.671 us; speedup vs baseline: 1.3067x; 1.0631x over previous
//
#include <hip/hip_runtime.h>

#define ROI_OUT_H 7
#define ROI_OUT_W 7
#define ROI_SPATIAL_SCALE 0.125f

// features: (B=8, C=256, H=100, W=100) fp32 NCHW
// rois:     (N, 5) fp32  [batch_idx, x1, y1, x2, y2]
// out:      (N, C, 7, 7) fp32

// ---------------------------------------------------------------------------
// Kernel 1: NCHW -> NHWC transpose over flat HW (64c x 64hw tile).
// Flat-HW tiling: transpose doesn't care about the y/x split, so tiles span
// row boundaries -> only the last of 157 hw-tiles has idle lanes (2% waste
// vs 22% with per-row x-tiles).
// ---------------------------------------------------------------------------
__global__ __launch_bounds__(256) void nchw_to_nhwc_flat(
    const float* __restrict__ src, float* __restrict__ dst)
{
    constexpr int C = 256, HW = 10000, NST = 157;
    __shared__ float tile[64][65];

    int bid = blockIdx.x;
    int ct = bid & 3;              // 4 c-tiles of 64
    int st = (bid >> 2) % NST;     // 157 hw-tiles of 64
    int b  = bid / (4 * NST);
    int c0 = ct * 64, s0 = st * 64;

    int t  = threadIdx.x;

    // load: float4 along hw. 16 quads x 16 c-rows per iter.
    int sq = t & 15, cr = t >> 4;
    #pragma unroll
    for (int i = 0; i < 4; ++i) {
        int c = i * 16 + cr;
        int s = s0 + 4 * sq;
        if (s + 3 < HW) {
            const float4 v = *reinterpret_cast<const float4*>(
                &src[((size_t)b * C + c0 + c) * HW + s]);
            tile[c][4 * sq + 0] = v.x;
            tile[c][4 * sq + 1] = v.y;
            tile[c][4 * sq + 2] = v.z;
            tile[c][4 * sq + 3] = v.w;
        } else {
            for (int j = 0; j < 4; ++j)
                if (s + j < HW)
                    tile[c][4 * sq + j] = src[((size_t)b * C + c0 + c) * HW + s + j];
        }
    }
    __syncthreads();

    // store: float4 along c. 16 c-quads x 16 hw-rows per iter.
    int cq = t & 15, sr = t >> 4;
    #pragma unroll
    for (int i = 0; i < 4; ++i) {
        int sl = i * 16 + sr;
        int s  = s0 + sl;
        if (s < HW) {
            float4 v;
            v.x = tile[4 * cq + 0][sl];
            v.y = tile[4 * cq + 1][sl];
            v.z = tile[4 * cq + 2][sl];
            v.w = tile[4 * cq + 3][sl];
            *reinterpret_cast<float4*>(
                &dst[((size_t)b * HW + s) * C + c0 + 4 * cq]) = v;
        }
    }
}

// ---------------------------------------------------------------------------
// Kernel 2: RoIAlign on NHWC, float4 gathers.
// One WAVE per (roi, c-quarter). lane = (bin-group g, channel-quad ci):
// 16 lanes x float4 = 64 channels per corner load (1 KB/wave-instr), and the
// 4 bin-groups issue 4 different bins' corners in the same instruction.
// ~208 vmem instrs/block vs 784 scalar before.
// ---------------------------------------------------------------------------
__global__ __launch_bounds__(64) void roi_align_nhwc_v4(
    const float* __restrict__ nhwc,
    const float* __restrict__ rois,
    float* __restrict__ out,
    int nwg)
{
    constexpr int C = 256, H = 100, W = 100;
    __shared__ float sbuf[64 * 49];   // [c_local][bin] == out sub-block layout

    // bijective XCD swizzle (m204)
    int bid = blockIdx.x;
    int q = nwg >> 3, r = nwg & 7;
    int xcd = bid & 7, pos = bid >> 3;
    int logical = (xcd < r ? xcd * (q + 1) : r * (q + 1) + (xcd - r) * q) + pos;

    int n  = logical >> 2;
    int cq = logical & 3;
    int c0 = cq * 64;

    int lane = threadIdx.x;
    int g  = lane >> 4;     // bin group: handles bins k ≡ g (mod 4)
    int ci = lane & 15;     // channel quad: channels c0 + 4*ci .. +3

    const float* roi = rois + (size_t)n * 5;
    int   b  = (int)roi[0];
    float x1 = roi[1] * ROI_SPATIAL_SCALE;
    float y1 = roi[2] * ROI_SPATIAL_SCALE;
    float x2 = roi[3] * ROI_SPATIAL_SCALE;
    float y2 = roi[4] * ROI_SPATIAL_SCALE;

    float roi_w = fmaxf(x2 - x1, 1.0f);
    float roi_h = fmaxf(y2 - y1, 1.0f);
    float bin_w = roi_w * (1.0f / ROI_OUT_W);
    float bin_h = roi_h * (1.0f / ROI_OUT_H);

    const float* img = nhwc + (size_t)b * (H * W * C) + c0 + 4 * ci;

    #pragma unroll
    for (int i = 0; i < 13; ++i) {
        int k = i * 4 + g;            // bin index for this lane's group
        if (k < 49) {
            int ph = k / 7;
            int pw = k - 7 * ph;

            float ax = 0.f, ay = 0.f, az = 0.f, aw = 0.f;

            #pragma unroll
            for (int sy = 0; sy < 2; ++sy) {
                float yy = y1 + (float)ph * bin_h + ((float)sy + 0.5f) * bin_h * 0.5f;
                float vy = (yy > -1.0f && yy < (float)H) ? 1.0f : 0.0f;
                float yc = fmaxf(yy, 0.0f);
                int y_low = (int)floorf(yc);
                int y_high;
                if (y_low >= H - 1) { y_low = H - 1; y_high = H - 1; yc = (float)y_low; }
                else                { y_high = y_low + 1; }
                float ly = (yc - (float)y_low) * vy;
                float hy = (1.0f - (yc - (float)y_low)) * vy;

                #pragma unroll
                for (int sx = 0; sx < 2; ++sx) {
                    float xx = x1 + (float)pw * bin_w + ((float)sx + 0.5f) * bin_w * 0.5f;
                    float vx = (xx > -1.0f && xx < (float)W) ? 1.0f : 0.0f;
                    float xc = fmaxf(xx, 0.0f);
                    int x_low = (int)floorf(xc);
                    int x_high;
                    if (x_low >= W - 1) { x_low = W - 1; x_high = W - 1; xc = (float)x_low; }
                    else                { x_high = x_low + 1; }
                    float lx = (xc - (float)x_low) * vx;
                    float hx = (1.0f - (xc - (float)x_low)) * vx;

                    float w1 = hy * hx, w2 = hy * lx, w3 = ly * hx, w4 = ly * lx;

                    const float4 v1 = *reinterpret_cast<const float4*>(&img[(y_low  * W + x_low ) * C]);
                    const float4 v2 = *reinterpret_cast<const float4*>(&img[(y_low  * W + x_high) * C]);
                    const float4 v3 = *reinterpret_cast<const float4*>(&img[(y_high * W + x_low ) * C]);
                    const float4 v4 = *reinterpret_cast<const float4*>(&img[(y_high * W + x_high) * C]);

                    ax += w1 * v1.x + w2 * v2.x + w3 * v3.x + w4 * v4.x;
                    ay += w1 * v1.y + w2 * v2.y + w3 * v3.y + w4 * v4.y;
                    az += w1 * v1.z + w2 * v2.z + w3 * v3.z + w4 * v4.z;
                    aw += w1 * v1.w + w2 * v2.w + w3 * v3.w + w4 * v4.w;
                }
            }

            sbuf[(4 * ci + 0) * 49 + k] = ax * 0.25f;
            sbuf[(4 * ci + 1) * 49 + k] = ay * 0.25f;
            sbuf[(4 * ci + 2) * 49 + k] = az * 0.25f;
            sbuf[(4 * ci + 3) * 49 + k] = aw * 0.25f;
        }
    }
    __syncthreads();

    // out sub-block (n, c0..c0+63) is 3136 contiguous floats, identity with sbuf
    size_t obase = (size_t)n * (C * 49) + (size_t)c0 * 49;
    #pragma unroll
    for (int i = 0; i < 49; ++i) {
        out[obase + i * 64 + lane] = sbuf[i * 64 + lane];
    }
}

// ---------------------------------------------------------------------------
// Fallback (round-0 kernel) if workspace is too small for the NHWC copy
// ---------------------------------------------------------------------------
__global__ __launch_bounds__(256) void roi_align_kernel(
    const float* __restrict__ features,
    const float* __restrict__ rois,
    float* __restrict__ out,
    int n_total, int C, int H, int W)
{
    const int HW = H * W;
    int idx = blockIdx.x * 256 + threadIdx.x;
    if (idx >= n_total) return;

    int pw  = idx % ROI_OUT_W;
    int ph  = (idx / ROI_OUT_W) % ROI_OUT_H;
    int c   = (idx / (ROI_OUT_H * ROI_OUT_W)) % 256;
    int n   = idx / (ROI_OUT_H * ROI_OUT_W * 256);

    const float* roi = rois + (size_t)n * 5;
    int   b  = (int)roi[0];
    float x1 = roi[1] * ROI_SPATIAL_SCALE;
    float y1 = roi[2] * ROI_SPATIAL_SCALE;
    float x2 = roi[3] * ROI_SPATIAL_SCALE;
    float y2 = roi[4] * ROI_SPATIAL_SCALE;

    float roi_w = fmaxf(x2 - x1, 1.0f);
    float roi_h = fmaxf(y2 - y1, 1.0f);
    float bin_w = roi_w * (1.0f / ROI_OUT_W);
    float bin_h = roi_h * (1.0f / ROI_OUT_H);

    const float* img = features + ((size_t)b * C + c) * HW;
    float acc = 0.0f;

    #pragma unroll
    for (int sy = 0; sy < 2; ++sy) {
        float y = y1 + (float)ph * bin_h + ((float)sy + 0.5f) * bin_h * 0.5f;
        bool  vy = (y > -1.0f) && (y < (float)H);
        float yc = fmaxf(y, 0.0f);
        int   y_low = (int)floorf(yc);
        int   y_high;
        if (y_low >= H - 1) { y_low = H - 1; y_high = H - 1; yc = (float)y_low; }
        else                { y_high = y_low + 1; }
        float ly = yc - (float)y_low;
        float hy = 1.0f - ly;

        #pragma unroll
        for (int sx = 0; sx < 2; ++sx) {
            float x = x1 + (float)pw * bin_w + ((float)sx + 0.5f) * bin_w * 0.5f;
            bool  vx = (x > -1.0f) && (x < (float)W);
            float xc = fmaxf(x, 0.0f);
            int   x_low = (int)floorf(xc);
            int   x_high;
            if (x_low >= W - 1) { x_low = W - 1; x_high = W - 1; xc = (float)x_low; }
            else                { x_high = x_low + 1; }
            float lx = xc - (float)x_low;
            float hx = 1.0f - lx;

            int base_lo = y_low  * W;
            int base_hi = y_high * W;
            float v1 = img[base_lo + x_low];
            float v2 = img[base_lo + x_high];
            float v3 = img[base_hi + x_low];
            float v4 = img[base_hi + x_high];

            float val = hy * hx * v1 + hy * lx * v2 + ly * hx * v3 + ly * lx * v4;
            acc += (vy && vx) ? val : 0.0f;
        }
    }
    out[idx] = acc * 0.25f;
}

extern "C" void kernel_launch(void* const* d_in, const int* in_sizes, int n_in,
                              void* d_out, int out_size, void* d_ws, size_t ws_size,
                              hipStream_t stream)
{
    const float* features = (const float*)d_in[0];
    const float* rois     = (const float*)d_in[1];
    float*       out      = (float*)d_out;

    const int C = 256, H = 100, W = 100, B = 8;
    int n_rois = in_sizes[1] / 5;   // 1000

    size_t nhwc_bytes = (size_t)B * H * W * C * sizeof(float);  // 81.92 MB

    if (ws_size >= nhwc_bytes) {
        float* nhwc = (float*)d_ws;
        nchw_to_nhwc_flat<<<B * 4 * 157, 256, 0, stream>>>(features, nhwc);
        int nwg = n_rois * 4;
        roi_align_nhwc_v4<<<nwg, 64, 0, stream>>>(nhwc, rois, out, nwg);
    } else {
        int n_total = n_rois * C * ROI_OUT_H * ROI_OUT_W;
        int grid = (n_total + 255) / 256;
        roi_align_kernel<<<grid, 256, 0, stream>>>(features, rois, out, n_total, C, H, W);
    }
}

// Round 6
// 172.844 us; speedup vs baseline: 1.5473x; 1.1841x over previous
//
#include <hip/hip_runtime.h>

#define ROI_OUT_H 7
#define ROI_OUT_W 7
#define ROI_SPATIAL_SCALE 0.125f

// features: (B=8, C=256, H=100, W=100) fp32 NCHW
// rois:     (N, 5) fp32  [batch_idx, x1, y1, x2, y2]
// out:      (N, C, 7, 7) fp32
// intermediate: NHWC bf16 in d_ws (B*HW*C*2 = 40.96 MB)

__device__ __forceinline__ unsigned short f2bf_rne(float f) {
    unsigned int u = __float_as_uint(f);
    u += 0x7fffu + ((u >> 16) & 1u);
    return (unsigned short)(u >> 16);
}

// ---------------------------------------------------------------------------
// Kernel 1: NCHW fp32 -> NHWC bf16 transpose over flat HW (64c x 64hw tile).
// ---------------------------------------------------------------------------
__global__ __launch_bounds__(256) void nchw_to_nhwc_bf16(
    const float* __restrict__ src, unsigned short* __restrict__ dst)
{
    constexpr int C = 256, HW = 10000, NST = 157;
    __shared__ float tile[64][65];

    int bid = blockIdx.x;
    int ct = bid & 3;              // 4 c-tiles of 64
    int st = (bid >> 2) % NST;     // 157 hw-tiles of 64
    int b  = bid / (4 * NST);
    int c0 = ct * 64, s0 = st * 64;

    int t = threadIdx.x;

    // load: float4 along hw. 16 quads x 16 c-rows per iter.
    int sq = t & 15, cr = t >> 4;
    #pragma unroll
    for (int i = 0; i < 4; ++i) {
        int c = i * 16 + cr;
        int s = s0 + 4 * sq;
        if (s + 3 < HW) {
            const float4 v = *reinterpret_cast<const float4*>(
                &src[((size_t)b * C + c0 + c) * HW + s]);
            tile[c][4 * sq + 0] = v.x;
            tile[c][4 * sq + 1] = v.y;
            tile[c][4 * sq + 2] = v.z;
            tile[c][4 * sq + 3] = v.w;
        } else {
            for (int j = 0; j < 4; ++j)
                if (s + j < HW)
                    tile[c][4 * sq + j] = src[((size_t)b * C + c0 + c) * HW + s + j];
        }
    }
    __syncthreads();

    // store: 4 channels as bf16x4 = 8 B per lane; 16-lane group = 128 B contig.
    int cq = t & 15, sr = t >> 4;
    #pragma unroll
    for (int i = 0; i < 4; ++i) {
        int sl = i * 16 + sr;
        int s  = s0 + sl;
        if (s < HW) {
            ushort4 v;
            v.x = f2bf_rne(tile[4 * cq + 0][sl]);
            v.y = f2bf_rne(tile[4 * cq + 1][sl]);
            v.z = f2bf_rne(tile[4 * cq + 2][sl]);
            v.w = f2bf_rne(tile[4 * cq + 3][sl]);
            *reinterpret_cast<ushort4*>(
                &dst[((size_t)b * HW + s) * C + c0 + 4 * cq]) = v;
        }
    }
}

// ---------------------------------------------------------------------------
// Kernel 2: RoIAlign on NHWC bf16.
// One WAVE per (roi, c-quarter). lane = (bin-group g in [0,8), channel-oct
// ci in [0,8)): 8 lanes x 8 bf16 channels (uint4, 16 B) = 64 channels per
// corner load; 8 bin-groups run 8 bins concurrently per instruction.
// 112 vmem loads per lane (vs 208 fp32-float4).
// ---------------------------------------------------------------------------
__global__ __launch_bounds__(64) void roi_align_nhwc_bf16(
    const unsigned short* __restrict__ nhwc,
    const float* __restrict__ rois,
    float* __restrict__ out,
    int nwg)
{
    constexpr int C = 256, H = 100, W = 100;
    __shared__ float sbuf[64 * 49];   // [c_local][bin] == out sub-block layout

    // bijective XCD swizzle (m204)
    int bid = blockIdx.x;
    int q = nwg >> 3, r = nwg & 7;
    int xcd = bid & 7, pos = bid >> 3;
    int logical = (xcd < r ? xcd * (q + 1) : r * (q + 1) + (xcd - r) * q) + pos;

    int n  = logical >> 2;
    int cq = logical & 3;
    int c0 = cq * 64;

    int lane = threadIdx.x;
    int g  = lane >> 3;     // bin group: bins k ≡ g (mod 8)
    int ci = lane & 7;      // channel oct: channels c0 + 8*ci .. +7

    const float* roi = rois + (size_t)n * 5;
    int   b  = (int)roi[0];
    float x1 = roi[1] * ROI_SPATIAL_SCALE;
    float y1 = roi[2] * ROI_SPATIAL_SCALE;
    float x2 = roi[3] * ROI_SPATIAL_SCALE;
    float y2 = roi[4] * ROI_SPATIAL_SCALE;

    float roi_w = fmaxf(x2 - x1, 1.0f);
    float roi_h = fmaxf(y2 - y1, 1.0f);
    float bin_w = roi_w * (1.0f / ROI_OUT_W);
    float bin_h = roi_h * (1.0f / ROI_OUT_H);

    const unsigned short* img = nhwc + (size_t)b * (H * W * C) + c0 + 8 * ci;

    #pragma unroll
    for (int i = 0; i < 7; ++i) {
        int k = i * 8 + g;            // bin index for this lane's group
        if (k < 49) {
            int ph = k / 7;
            int pw = k - 7 * ph;

            float a0 = 0.f, a1 = 0.f, a2 = 0.f, a3 = 0.f;
            float a4 = 0.f, a5 = 0.f, a6 = 0.f, a7 = 0.f;

            #pragma unroll
            for (int sy = 0; sy < 2; ++sy) {
                float yy = y1 + (float)ph * bin_h + ((float)sy + 0.5f) * bin_h * 0.5f;
                float vy = (yy > -1.0f && yy < (float)H) ? 1.0f : 0.0f;
                float yc = fmaxf(yy, 0.0f);
                int y_low = (int)floorf(yc);
                int y_high;
                if (y_low >= H - 1) { y_low = H - 1; y_high = H - 1; yc = (float)y_low; }
                else                { y_high = y_low + 1; }
                float fy = yc - (float)y_low;
                float ly = fy * vy;
                float hy = (1.0f - fy) * vy;

                #pragma unroll
                for (int sx = 0; sx < 2; ++sx) {
                    float xx = x1 + (float)pw * bin_w + ((float)sx + 0.5f) * bin_w * 0.5f;
                    float vx = (xx > -1.0f && xx < (float)W) ? 1.0f : 0.0f;
                    float xc = fmaxf(xx, 0.0f);
                    int x_low = (int)floorf(xc);
                    int x_high;
                    if (x_low >= W - 1) { x_low = W - 1; x_high = W - 1; xc = (float)x_low; }
                    else                { x_high = x_low + 1; }
                    float fx = xc - (float)x_low;
                    float lx = fx * vx;
                    float hx = (1.0f - fx) * vx;

                    float w1 = hy * hx, w2 = hy * lx, w3 = ly * hx, w4 = ly * lx;

                    const uint4 q1 = *reinterpret_cast<const uint4*>(&img[(y_low  * W + x_low ) * C]);
                    const uint4 q2 = *reinterpret_cast<const uint4*>(&img[(y_low  * W + x_high) * C]);
                    const uint4 q3 = *reinterpret_cast<const uint4*>(&img[(y_high * W + x_low ) * C]);
                    const uint4 q4 = *reinterpret_cast<const uint4*>(&img[(y_high * W + x_high) * C]);

                    #define BF_LO(u) __uint_as_float((u) << 16)
                    #define BF_HI(u) __uint_as_float((u) & 0xffff0000u)
                    a0 += w1 * BF_LO(q1.x) + w2 * BF_LO(q2.x) + w3 * BF_LO(q3.x) + w4 * BF_LO(q4.x);
                    a1 += w1 * BF_HI(q1.x) + w2 * BF_HI(q2.x) + w3 * BF_HI(q3.x) + w4 * BF_HI(q4.x);
                    a2 += w1 * BF_LO(q1.y) + w2 * BF_LO(q2.y) + w3 * BF_LO(q3.y) + w4 * BF_LO(q4.y);
                    a3 += w1 * BF_HI(q1.y) + w2 * BF_HI(q2.y) + w3 * BF_HI(q3.y) + w4 * BF_HI(q4.y);
                    a4 += w1 * BF_LO(q1.z) + w2 * BF_LO(q2.z) + w3 * BF_LO(q3.z) + w4 * BF_LO(q4.z);
                    a5 += w1 * BF_HI(q1.z) + w2 * BF_HI(q2.z) + w3 * BF_HI(q3.z) + w4 * BF_HI(q4.z);
                    a6 += w1 * BF_LO(q1.w) + w2 * BF_LO(q2.w) + w3 * BF_LO(q3.w) + w4 * BF_LO(q4.w);
                    a7 += w1 * BF_HI(q1.w) + w2 * BF_HI(q2.w) + w3 * BF_HI(q3.w) + w4 * BF_HI(q4.w);
                    #undef BF_LO
                    #undef BF_HI
                }
            }

            int cl = 8 * ci;
            sbuf[(cl + 0) * 49 + k] = a0 * 0.25f;
            sbuf[(cl + 1) * 49 + k] = a1 * 0.25f;
            sbuf[(cl + 2) * 49 + k] = a2 * 0.25f;
            sbuf[(cl + 3) * 49 + k] = a3 * 0.25f;
            sbuf[(cl + 4) * 49 + k] = a4 * 0.25f;
            sbuf[(cl + 5) * 49 + k] = a5 * 0.25f;
            sbuf[(cl + 6) * 49 + k] = a6 * 0.25f;
            sbuf[(cl + 7) * 49 + k] = a7 * 0.25f;
        }
    }
    __syncthreads();

    // out sub-block (n, c0..c0+63) = 3136 contiguous floats, identity with sbuf
    size_t obase = (size_t)n * (C * 49) + (size_t)c0 * 49;
    #pragma unroll
    for (int i = 0; i < 49; ++i) {
        out[obase + i * 64 + lane] = sbuf[i * 64 + lane];
    }
}

// ---------------------------------------------------------------------------
// Fallback (round-0 kernel) if workspace is too small
// ---------------------------------------------------------------------------
__global__ __launch_bounds__(256) void roi_align_kernel(
    const float* __restrict__ features,
    const float* __restrict__ rois,
    float* __restrict__ out,
    int n_total, int C, int H, int W)
{
    const int HW = H * W;
    int idx = blockIdx.x * 256 + threadIdx.x;
    if (idx >= n_total) return;

    int pw  = idx % ROI_OUT_W;
    int ph  = (idx / ROI_OUT_W) % ROI_OUT_H;
    int c   = (idx / (ROI_OUT_H * ROI_OUT_W)) % 256;
    int n   = idx / (ROI_OUT_H * ROI_OUT_W * 256);

    const float* roi = rois + (size_t)n * 5;
    int   b  = (int)roi[0];
    float x1 = roi[1] * ROI_SPATIAL_SCALE;
    float y1 = roi[2] * ROI_SPATIAL_SCALE;
    float x2 = roi[3] * ROI_SPATIAL_SCALE;
    float y2 = roi[4] * ROI_SPATIAL_SCALE;

    float roi_w = fmaxf(x2 - x1, 1.0f);
    float roi_h = fmaxf(y2 - y1, 1.0f);
    float bin_w = roi_w * (1.0f / ROI_OUT_W);
    float bin_h = roi_h * (1.0f / ROI_OUT_H);

    const float* img = features + ((size_t)b * C + c) * HW;
    float acc = 0.0f;

    #pragma unroll
    for (int sy = 0; sy < 2; ++sy) {
        float y = y1 + (float)ph * bin_h + ((float)sy + 0.5f) * bin_h * 0.5f;
        bool  vy = (y > -1.0f) && (y < (float)H);
        float yc = fmaxf(y, 0.0f);
        int   y_low = (int)floorf(yc);
        int   y_high;
        if (y_low >= H - 1) { y_low = H - 1; y_high = H - 1; yc = (float)y_low; }
        else                { y_high = y_low + 1; }
        float ly = yc - (float)y_low;
        float hy = 1.0f - ly;

        #pragma unroll
        for (int sx = 0; sx < 2; ++sx) {
            float x = x1 + (float)pw * bin_w + ((float)sx + 0.5f) * bin_w * 0.5f;
            bool  vx = (x > -1.0f) && (x < (float)W);
            float xc = fmaxf(x, 0.0f);
            int   x_low = (int)floorf(xc);
            int   x_high;
            if (x_low >= W - 1) { x_low = W - 1; x_high = W - 1; xc = (float)x_low; }
            else                { x_high = x_low + 1; }
            float lx = xc - (float)x_low;
            float hx = 1.0f - lx;

            int base_lo = y_low  * W;
            int base_hi = y_high * W;
            float v1 = img[base_lo + x_low];
            float v2 = img[base_lo + x_high];
            float v3 = img[base_hi + x_low];
            float v4 = img[base_hi + x_high];

            float val = hy * hx * v1 + hy * lx * v2 + ly * hx * v3 + ly * lx * v4;
            acc += (vy && vx) ? val : 0.0f;
        }
    }
    out[idx] = acc * 0.25f;
}

extern "C" void kernel_launch(void* const* d_in, const int* in_sizes, int n_in,
                              void* d_out, int out_size, void* d_ws, size_t ws_size,
                              hipStream_t stream)
{
    const float* features = (const float*)d_in[0];
    const float* rois     = (const float*)d_in[1];
    float*       out      = (float*)d_out;

    const int C = 256, H = 100, W = 100, B = 8;
    int n_rois = in_sizes[1] / 5;   // 1000

    size_t nhwc_bytes = (size_t)B * H * W * C * sizeof(unsigned short);  // 40.96 MB

    if (ws_size >= nhwc_bytes) {
        unsigned short* nhwc = (unsigned short*)d_ws;
        nchw_to_nhwc_bf16<<<B * 4 * 157, 256, 0, stream>>>(features, nhwc);
        int nwg = n_rois * 4;
        roi_align_nhwc_bf16<<<nwg, 64, 0, stream>>>(nhwc, rois, out, nwg);
    } else {
        int n_total = n_rois * C * ROI_OUT_H * ROI_OUT_W;
        int grid = (n_total + 255) / 256;
        roi_align_kernel<<<grid, 256, 0, stream>>>(features, rois, out, n_total, C, H, W);
    }
}